// Round 3
// baseline (277.733 us; speedup 1.0000x reference)
//
#include <hip/hip_runtime.h>
#include <hip/hip_bf16.h>
#include <stdint.h>

#define T_TOK 2048
#define HDIM  1024
#define IDIM  768
#define NEXP  32
#define TOPK  4
#define NPAIR (T_TOK*TOPK)   // 8192
#define MTILE 256
#define MAXMT 64

typedef __attribute__((ext_vector_type(8))) short bf16x8;
typedef __attribute__((ext_vector_type(4))) float f32x4;

__device__ __forceinline__ unsigned short f2bf(float f){
  union { float f; unsigned u; } v; v.f = f;
  unsigned r = (v.u + 0x7fffu + ((v.u >> 16) & 1u)) >> 16;  // RNE
  return (unsigned short)r;
}

// ---------------- x fp32 -> bf16 ----------------
__global__ __launch_bounds__(256) void k_convert_x(const float* __restrict__ x,
                                                   ushort* __restrict__ xb){
  int idx = blockIdx.x*256 + threadIdx.x;
  float4 v = ((const float4*)x)[idx];
  ushort4 o; o.x=f2bf(v.x); o.y=f2bf(v.y); o.z=f2bf(v.z); o.w=f2bf(v.w);
  ((ushort4*)xb)[idx] = o;
}

// ---------------- router ----------------
__global__ __launch_bounds__(256) void k_router(const float* __restrict__ x,
                                                const float* __restrict__ gw,
                                                int* __restrict__ ei, float* __restrict__ wv,
                                                int* __restrict__ counts){
  int wid  = threadIdx.x >> 6;
  int lane = threadIdx.x & 63;
  int t = blockIdx.x*4 + wid;
  float xv[16];
  #pragma unroll
  for (int i=0;i<16;i++) xv[i] = x[t*HDIM + i*64 + lane];
  float p[NEXP];
  #pragma unroll
  for (int e=0;e<NEXP;e++){
    const float* w = gw + e*HDIM;
    float a = 0.f;
    #pragma unroll
    for (int i=0;i<16;i++) a = fmaf(xv[i], w[i*64+lane], a);
    #pragma unroll
    for (int off=32; off>=1; off>>=1) a += __shfl_xor(a, off, 64);
    p[e] = a;
  }
  float m = p[0];
  #pragma unroll
  for (int e=1;e<NEXP;e++) m = fmaxf(m, p[e]);
  #pragma unroll
  for (int e=0;e<NEXP;e++) p[e] = __expf(p[e]-m);
  unsigned used = 0; int sel[TOPK]; float sw[TOPK]; float wsum = 0.f;
  #pragma unroll
  for (int k=0;k<TOPK;k++){
    float best = -1.f; int bi = 0;
    #pragma unroll
    for (int e=0;e<NEXP;e++){
      bool ok = (((used>>e)&1u)==0u) && (p[e] > best);
      best = ok ? p[e] : best; bi = ok ? e : bi;
    }
    used |= 1u<<bi; sel[k]=bi; sw[k]=best; wsum += best;
  }
  if (lane==0){
    float inv = 1.f/wsum;
    #pragma unroll
    for (int k=0;k<TOPK;k++){
      ei[t*TOPK+k] = sel[k];
      wv[t*TOPK+k] = sw[k]*inv;
      atomicAdd(&counts[sel[k]], 1);
    }
  }
}

// ---------------- offsets + m-tile worklist ----------------
__global__ void k_offsets(const int* __restrict__ counts, int* __restrict__ offsets,
                          int* __restrict__ mtE, int* __restrict__ mtM0,
                          int* __restrict__ nmt){
  if (threadIdx.x==0 && blockIdx.x==0){
    int s=0;
    for (int e=0;e<NEXP;e++){ offsets[e]=s; s+=counts[e]; }
    offsets[NEXP]=s;
    int nm=0;
    for (int e=0;e<NEXP;e++){
      int ne = counts[e];
      for (int m0=0; m0<ne && nm<MAXMT; m0+=MTILE){ mtE[nm]=e; mtM0[nm]=m0; nm++; }
    }
    nmt[0]=nm;
  }
}

__global__ __launch_bounds__(256) void k_scatter(const int* __restrict__ ei,
                                                 const int* __restrict__ offsets,
                                                 int* __restrict__ cursor,
                                                 int* __restrict__ slot_tk,
                                                 int* __restrict__ tk_slot){
  int g = blockIdx.x*256 + threadIdx.x;
  int e = ei[g];
  int pos = atomicAdd(&cursor[e], 1);
  int slot = offsets[e] + pos;
  slot_tk[slot] = g;
  tk_slot[g] = slot;
}

// ---------------- gate+up GEMM + SiLU ----------------
// tile M=256 x N=48, BK=64, 16 K-steps; 8 waves x 32 rows; A direct-global, B LDS dbuf
__global__ __launch_bounds__(512,4) void k_gateup(const ushort* __restrict__ xb,
    const float* __restrict__ w1, const float* __restrict__ w3,
    const int* __restrict__ offsets, const int* __restrict__ slot_tk,
    const int* __restrict__ mtE, const int* __restrict__ mtM0, const int* __restrict__ nmt,
    ushort* __restrict__ act){
  int bi  = blockIdx.x;
  int mti = bi >> 4;
  int it  = bi & 15;
  if (mti >= nmt[0]) return;
  int e    = mtE[mti];
  int m0   = mtM0[mti];
  int off0 = offsets[e];
  int ne   = offsets[e+1]-off0;
  int ibase = it*48;

  __shared__ int toks[256];
  __shared__ ushort Bls[2][2][48][68];   // [buf][mat][row][k] +4 pad

  int tid = threadIdx.x, wid = tid>>6, lane = tid&63;
  if (tid < 256){
    int slot = off0 + m0 + tid;
    int fb = slot_tk[off0] >> 2;
    toks[tid] = (m0 + tid < ne) ? (slot_tk[slot] >> 2) : fb;
  }
  // B staging descriptors: 3 float4/thread per K-step
  const float* bsrc[3]; int b_mat[3], b_r[3], b_c4[3];
  const size_t wbase = (size_t)e * IDIM * HDIM;
  #pragma unroll
  for (int s=0;s<3;s++){
    int li = s*512 + tid;                // 0..1535
    int mat = li >= 768;
    int li2 = li - mat*768;
    int r = li2>>4, c4 = li2&15;
    b_mat[s]=mat; b_r[s]=r; b_c4[s]=c4;
    bsrc[s] = (mat ? w3 : w1) + wbase + (size_t)(ibase+r)*HDIM + c4*4;
  }
  __syncthreads();

  // A row tokens for this wave (2 m-frags of 16 rows)
  const ushort* arow[2];
  #pragma unroll
  for (int m=0;m<2;m++){
    int row = wid*32 + m*16 + (lane&15);
    arow[m] = xb + (size_t)toks[row]*HDIM + (lane>>4)*8;
  }

  f32x4 accg[2][3], accu[2][3];
  #pragma unroll
  for (int a=0;a<2;a++)
    #pragma unroll
    for (int b=0;b<3;b++){ accg[a][b]=(f32x4){0,0,0,0}; accu[a][b]=(f32x4){0,0,0,0}; }

  float4 breg[3];
  #pragma unroll
  for (int s=0;s<3;s++) breg[s] = *(const float4*)(bsrc[s]);
  #pragma unroll
  for (int s=0;s<3;s++){
    ushort4 o; o.x=f2bf(breg[s].x); o.y=f2bf(breg[s].y); o.z=f2bf(breg[s].z); o.w=f2bf(breg[s].w);
    *(ushort4*)(&Bls[0][b_mat[s]][b_r[s]][b_c4[s]*4]) = o;
  }
  __syncthreads();

  for (int kb=0; kb<16; ++kb){
    int cur = kb & 1, nxt = cur ^ 1;
    if (kb < 15){
      #pragma unroll
      for (int s=0;s<3;s++) breg[s] = *(const float4*)(bsrc[s] + (kb+1)*64);
    }
    #pragma unroll
    for (int kk=0; kk<2; ++kk){
      bf16x8 af[2];
      #pragma unroll
      for (int m=0;m<2;m++)
        af[m] = *(const bf16x8*)(arow[m] + kb*64 + kk*32);
      #pragma unroll
      for (int n=0;n<3;n++){
        bf16x8 bg = *(const bf16x8*)(&Bls[cur][0][n*16 + (lane&15)][kk*32 + (lane>>4)*8]);
        bf16x8 bu = *(const bf16x8*)(&Bls[cur][1][n*16 + (lane&15)][kk*32 + (lane>>4)*8]);
        #pragma unroll
        for (int m=0;m<2;m++){
          accg[m][n] = __builtin_amdgcn_mfma_f32_16x16x32_bf16(af[m], bg, accg[m][n], 0,0,0);
          accu[m][n] = __builtin_amdgcn_mfma_f32_16x16x32_bf16(af[m], bu, accu[m][n], 0,0,0);
        }
      }
    }
    if (kb < 15){
      #pragma unroll
      for (int s=0;s<3;s++){
        ushort4 o; o.x=f2bf(breg[s].x); o.y=f2bf(breg[s].y); o.z=f2bf(breg[s].z); o.w=f2bf(breg[s].w);
        *(ushort4*)(&Bls[nxt][b_mat[s]][b_r[s]][b_c4[s]*4]) = o;
      }
    }
    __syncthreads();
  }

  int nval = ne - m0; if (nval > 256) nval = 256;
  #pragma unroll
  for (int m=0;m<2;m++)
    #pragma unroll
    for (int n=0;n<3;n++)
      #pragma unroll
      for (int r=0;r<4;r++){
        int row = wid*32 + m*16 + (lane>>4)*4 + r;
        if (row < nval){
          float g = accg[m][n][r], u = accu[m][n][r];
          float sval = g / (1.f + __expf(-g)) * u;
          act[(size_t)(off0+m0+row)*IDIM + ibase + n*16 + (lane&15)] = f2bf(sval);
        }
      }
}

// ---------------- down GEMM ----------------
// tile M=256 x N=64, BK=64, 12 K-steps; 8 waves x 32 rows; A direct-global, B LDS dbuf
__global__ __launch_bounds__(512,4) void k_down(const ushort* __restrict__ act,
    const float* __restrict__ w2, const int* __restrict__ offsets,
    const int* __restrict__ mtE, const int* __restrict__ mtM0, const int* __restrict__ nmt,
    float* __restrict__ pout){
  int bi  = blockIdx.x;
  int mti = bi >> 4;
  int ht  = bi & 15;
  if (mti >= nmt[0]) return;
  int e    = mtE[mti];
  int m0   = mtM0[mti];
  int off0 = offsets[e], ne = offsets[e+1]-off0;
  int hbase = ht*64;

  __shared__ ushort Bls[2][64][68];

  int tid = threadIdx.x, wid = tid>>6, lane = tid&63;

  const float* bsrc[2]; int b_r[2], b_c4[2];
  const size_t wbase = (size_t)e * HDIM * IDIM;
  #pragma unroll
  for (int s=0;s<2;s++){
    int li = s*512 + tid;                // 0..1023
    int r = li>>4, c4 = li&15;
    b_r[s]=r; b_c4[s]=c4;
    bsrc[s] = w2 + wbase + (size_t)(hbase+r)*IDIM + c4*4;
  }

  const ushort* arow[2];
  #pragma unroll
  for (int m=0;m<2;m++){
    int row = wid*32 + m*16 + (lane&15);
    int mrow = m0 + row; mrow = (mrow < ne) ? mrow : 0;
    arow[m] = act + (size_t)(off0+mrow)*IDIM + (lane>>4)*8;
  }

  f32x4 acc[2][4];
  #pragma unroll
  for (int a=0;a<2;a++)
    #pragma unroll
    for (int b=0;b<4;b++) acc[a][b]=(f32x4){0,0,0,0};

  float4 breg[2];
  #pragma unroll
  for (int s=0;s<2;s++) breg[s] = *(const float4*)(bsrc[s]);
  #pragma unroll
  for (int s=0;s<2;s++){
    ushort4 o; o.x=f2bf(breg[s].x); o.y=f2bf(breg[s].y); o.z=f2bf(breg[s].z); o.w=f2bf(breg[s].w);
    *(ushort4*)(&Bls[0][b_r[s]][b_c4[s]*4]) = o;
  }
  __syncthreads();

  for (int kb=0; kb<12; ++kb){
    int cur = kb & 1, nxt = cur ^ 1;
    if (kb < 11){
      #pragma unroll
      for (int s=0;s<2;s++) breg[s] = *(const float4*)(bsrc[s] + (kb+1)*64);
    }
    #pragma unroll
    for (int kk=0; kk<2; ++kk){
      bf16x8 af[2];
      #pragma unroll
      for (int m=0;m<2;m++)
        af[m] = *(const bf16x8*)(arow[m] + kb*64 + kk*32);
      #pragma unroll
      for (int n=0;n<4;n++){
        bf16x8 bw = *(const bf16x8*)(&Bls[cur][n*16 + (lane&15)][kk*32 + (lane>>4)*8]);
        #pragma unroll
        for (int m=0;m<2;m++)
          acc[m][n] = __builtin_amdgcn_mfma_f32_16x16x32_bf16(af[m], bw, acc[m][n], 0,0,0);
      }
    }
    if (kb < 11){
      #pragma unroll
      for (int s=0;s<2;s++){
        ushort4 o; o.x=f2bf(breg[s].x); o.y=f2bf(breg[s].y); o.z=f2bf(breg[s].z); o.w=f2bf(breg[s].w);
        *(ushort4*)(&Bls[nxt][b_r[s]][b_c4[s]*4]) = o;
      }
    }
    __syncthreads();
  }

  int nval = ne - m0; if (nval > 256) nval = 256;
  #pragma unroll
  for (int m=0;m<2;m++)
    #pragma unroll
    for (int n=0;n<4;n++)
      #pragma unroll
      for (int r=0;r<4;r++){
        int row = wid*32 + m*16 + (lane>>4)*4 + r;
        if (row < nval)
          pout[(size_t)(off0+m0+row)*HDIM + hbase + n*16 + (lane&15)] = acc[m][n][r];
      }
}

// ---------------- combine ----------------
__global__ __launch_bounds__(256) void k_combine(const float* __restrict__ pout,
    const int* __restrict__ tk_slot, const float* __restrict__ wv,
    float* __restrict__ out){
  int t = blockIdx.x;
  int c = threadIdx.x;
  float a0=0,a1=0,a2=0,a3=0;
  #pragma unroll
  for (int k=0;k<TOPK;k++){
    int slot = tk_slot[t*TOPK+k];
    float w  = wv[t*TOPK+k];
    float4 v = *(const float4*)(pout + (size_t)slot*HDIM + c*4);
    a0 = fmaf(w, v.x, a0); a1 = fmaf(w, v.y, a1);
    a2 = fmaf(w, v.z, a2); a3 = fmaf(w, v.w, a3);
  }
  float4 o; o.x=a0; o.y=a1; o.z=a2; o.w=a3;
  *(float4*)(out + (size_t)t*HDIM + c*4) = o;
}

extern "C" void kernel_launch(void* const* d_in, const int* in_sizes, int n_in,
                              void* d_out, int out_size, void* d_ws, size_t ws_size,
                              hipStream_t stream){
  const float* x  = (const float*)d_in[0];
  const float* gw = (const float*)d_in[1];
  const float* w1 = (const float*)d_in[2];
  const float* w3 = (const float*)d_in[3];
  const float* w2 = (const float*)d_in[4];
  float* out = (float*)d_out;

  char* ws = (char*)d_ws;
  size_t off = 0;
  ushort* xb   = (ushort*)(ws + off); off += (size_t)T_TOK*HDIM*2;
  ushort* act  = (ushort*)(ws + off); off += (size_t)NPAIR*IDIM*2;
  float*  pout = (float*) (ws + off); off += (size_t)NPAIR*HDIM*4;
  int* counts  = (int*)(ws + off); off += NEXP*4;
  int* cursor  = (int*)(ws + off); off += NEXP*4;
  int* offsets = (int*)(ws + off); off += (NEXP+1)*4;
  int* mtE     = (int*)(ws + off); off += MAXMT*4;
  int* mtM0    = (int*)(ws + off); off += MAXMT*4;
  int* nmt     = (int*)(ws + off); off += 4;
  off = (off + 255) & ~(size_t)255;
  int*   ei      = (int*)  (ws + off); off += (size_t)NPAIR*4;
  float* wvp     = (float*)(ws + off); off += (size_t)NPAIR*4;
  int*   slot_tk = (int*)  (ws + off); off += (size_t)NPAIR*4;
  int*   tk_slot = (int*)  (ws + off); off += (size_t)NPAIR*4;

  hipMemsetAsync(counts, 0, 2*NEXP*4, stream);

  k_convert_x<<<T_TOK*HDIM/1024, 256, 0, stream>>>(x, xb);
  k_router<<<T_TOK/4, 256, 0, stream>>>(x, gw, ei, wvp, counts);
  k_offsets<<<1, 64, 0, stream>>>(counts, offsets, mtE, mtM0, nmt);
  k_scatter<<<NPAIR/256, 256, 0, stream>>>(ei, offsets, cursor, slot_tk, tk_slot);
  k_gateup<<<MAXMT*16, 512, 0, stream>>>(xb, w1, w3, offsets, slot_tk, mtE, mtM0, nmt, act);
  k_down<<<MAXMT*16, 512, 0, stream>>>(act, w2, offsets, mtE, mtM0, nmt, pout);
  k_combine<<<T_TOK, 256, 0, stream>>>(pout, tk_slot, wvp, out);
}

// Round 4
// 242.905 us; speedup vs baseline: 1.1434x; 1.1434x over previous
//
#include <hip/hip_runtime.h>
#include <hip/hip_bf16.h>
#include <stdint.h>

#define T_TOK 2048
#define HDIM  1024
#define IDIM  768
#define NEXP  32
#define TOPK  4
#define NPAIR (T_TOK*TOPK)   // 8192
#define MTILE 256
#define MAXMT 64

typedef __attribute__((ext_vector_type(8))) short bf16x8;
typedef __attribute__((ext_vector_type(4))) float f32x4;

__device__ __forceinline__ unsigned short f2bf(float f){
  union { float f; unsigned u; } v; v.f = f;
  unsigned r = (v.u + 0x7fffu + ((v.u >> 16) & 1u)) >> 16;  // RNE
  return (unsigned short)r;
}

// ---------------- x fp32 -> bf16 ----------------
__global__ __launch_bounds__(256) void k_convert_x(const float* __restrict__ x,
                                                   ushort* __restrict__ xb){
  int idx = blockIdx.x*256 + threadIdx.x;
  float4 v = ((const float4*)x)[idx];
  ushort4 o; o.x=f2bf(v.x); o.y=f2bf(v.y); o.z=f2bf(v.z); o.w=f2bf(v.w);
  ((ushort4*)xb)[idx] = o;
}

// ---------------- router ----------------
__global__ __launch_bounds__(256) void k_router(const float* __restrict__ x,
                                                const float* __restrict__ gw,
                                                int* __restrict__ ei, float* __restrict__ wv,
                                                int* __restrict__ counts){
  int wid  = threadIdx.x >> 6;
  int lane = threadIdx.x & 63;
  int t = blockIdx.x*4 + wid;
  float xv[16];
  #pragma unroll
  for (int i=0;i<16;i++) xv[i] = x[t*HDIM + i*64 + lane];
  float p[NEXP];
  #pragma unroll
  for (int e=0;e<NEXP;e++){
    const float* w = gw + e*HDIM;
    float a = 0.f;
    #pragma unroll
    for (int i=0;i<16;i++) a = fmaf(xv[i], w[i*64+lane], a);
    #pragma unroll
    for (int off=32; off>=1; off>>=1) a += __shfl_xor(a, off, 64);
    p[e] = a;
  }
  float m = p[0];
  #pragma unroll
  for (int e=1;e<NEXP;e++) m = fmaxf(m, p[e]);
  #pragma unroll
  for (int e=0;e<NEXP;e++) p[e] = __expf(p[e]-m);
  unsigned used = 0; int sel[TOPK]; float sw[TOPK]; float wsum = 0.f;
  #pragma unroll
  for (int k=0;k<TOPK;k++){
    float best = -1.f; int bi = 0;
    #pragma unroll
    for (int e=0;e<NEXP;e++){
      bool ok = (((used>>e)&1u)==0u) && (p[e] > best);
      best = ok ? p[e] : best; bi = ok ? e : bi;
    }
    used |= 1u<<bi; sel[k]=bi; sw[k]=best; wsum += best;
  }
  if (lane==0){
    float inv = 1.f/wsum;
    #pragma unroll
    for (int k=0;k<TOPK;k++){
      ei[t*TOPK+k] = sel[k];
      wv[t*TOPK+k] = sw[k]*inv;
      atomicAdd(&counts[sel[k]], 1);
    }
  }
}

// ---------------- offsets + m-tile worklist ----------------
__global__ void k_offsets(const int* __restrict__ counts, int* __restrict__ offsets,
                          int* __restrict__ mtE, int* __restrict__ mtM0,
                          int* __restrict__ nmt){
  if (threadIdx.x==0 && blockIdx.x==0){
    int s=0;
    for (int e=0;e<NEXP;e++){ offsets[e]=s; s+=counts[e]; }
    offsets[NEXP]=s;
    int nm=0;
    for (int e=0;e<NEXP;e++){
      int ne = counts[e];
      for (int m0=0; m0<ne && nm<MAXMT; m0+=MTILE){ mtE[nm]=e; mtM0[nm]=m0; nm++; }
    }
    nmt[0]=nm;
  }
}

__global__ __launch_bounds__(256) void k_scatter(const int* __restrict__ ei,
                                                 const int* __restrict__ offsets,
                                                 int* __restrict__ cursor,
                                                 int* __restrict__ slot_tk,
                                                 int* __restrict__ tk_slot){
  int g = blockIdx.x*256 + threadIdx.x;
  int e = ei[g];
  int pos = atomicAdd(&cursor[e], 1);
  int slot = offsets[e] + pos;
  slot_tk[slot] = g;
  tk_slot[g] = slot;
}

// ---------------- gate+up GEMM + SiLU ----------------
// tile M=256 x N=32, BK=64, 16 K-steps; 8 waves x 32 rows
// A: per-lane global frags, reg-prefetched 1 step; B: LDS dbuf, reg-prefetch depth 2
__global__ __launch_bounds__(512,4) void k_gateup(const ushort* __restrict__ xb,
    const float* __restrict__ w1, const float* __restrict__ w3,
    const int* __restrict__ offsets, const int* __restrict__ slot_tk,
    const int* __restrict__ mtE, const int* __restrict__ mtM0, const int* __restrict__ nmt,
    ushort* __restrict__ act){
  int bi  = blockIdx.x;
  int mti = bi / 24;
  int it  = bi - mti*24;
  if (mti >= nmt[0]) return;
  int e    = mtE[mti];
  int m0   = mtM0[mti];
  int off0 = offsets[e];
  int ne   = offsets[e+1]-off0;
  int ibase = it*32;

  __shared__ int toks[256];
  __shared__ ushort Bls[2][2][32][68];   // [buf][mat][row][k] +4 pad

  int tid = threadIdx.x, wid = tid>>6, lane = tid&63;
  if (tid < 256){
    int slot = off0 + m0 + tid;
    int fb = slot_tk[off0] >> 2;
    toks[tid] = (m0 + tid < ne) ? (slot_tk[slot] >> 2) : fb;
  }
  int b_r = tid>>4, b_c4 = tid&15;       // 32 rows x 16 c4-chunks
  const size_t wbase = (size_t)e * IDIM * HDIM;
  const float* bsrc0 = w1 + wbase + (size_t)(ibase+b_r)*HDIM + b_c4*4;
  const float* bsrc1 = w3 + wbase + (size_t)(ibase+b_r)*HDIM + b_c4*4;
  __syncthreads();

  const ushort* arow0 = xb + (size_t)toks[wid*32      + (lane&15)]*HDIM + (lane>>4)*8;
  const ushort* arow1 = xb + (size_t)toks[wid*32 + 16 + (lane&15)]*HDIM + (lane>>4)*8;

  f32x4 accg[2][2], accu[2][2];
  #pragma unroll
  for (int a=0;a<2;a++)
    #pragma unroll
    for (int b=0;b<2;b++){ accg[a][b]=(f32x4){0,0,0,0}; accu[a][b]=(f32x4){0,0,0,0}; }

  float4 bP[2], bQ[2];
  bf16x8 afA[4], afB[4];

  auto loadB = [&](int kb, float4* d){
    d[0] = *(const float4*)(bsrc0 + kb*64);
    d[1] = *(const float4*)(bsrc1 + kb*64);
  };
  auto loadA = [&](int kb, bf16x8* d){
    #pragma unroll
    for (int kk=0;kk<2;kk++){
      d[kk*2+0] = *(const bf16x8*)(arow0 + kb*64 + kk*32);
      d[kk*2+1] = *(const bf16x8*)(arow1 + kb*64 + kk*32);
    }
  };
  auto writeB = [&](int buf, const float4* s){
    #pragma unroll
    for (int m=0;m<2;m++){
      ushort4 o; o.x=f2bf(s[m].x); o.y=f2bf(s[m].y); o.z=f2bf(s[m].z); o.w=f2bf(s[m].w);
      *(ushort4*)(&Bls[buf][m][b_r][b_c4*4]) = o;
    }
  };
  auto compute = [&](int buf, const bf16x8* af){
    #pragma unroll
    for (int kk=0;kk<2;kk++){
      #pragma unroll
      for (int n=0;n<2;n++){
        bf16x8 bg = *(const bf16x8*)(&Bls[buf][0][n*16 + (lane&15)][kk*32 + (lane>>4)*8]);
        bf16x8 bu = *(const bf16x8*)(&Bls[buf][1][n*16 + (lane&15)][kk*32 + (lane>>4)*8]);
        #pragma unroll
        for (int m=0;m<2;m++){
          accg[m][n] = __builtin_amdgcn_mfma_f32_16x16x32_bf16(af[kk*2+m], bg, accg[m][n], 0,0,0);
          accu[m][n] = __builtin_amdgcn_mfma_f32_16x16x32_bf16(af[kk*2+m], bu, accu[m][n], 0,0,0);
        }
      }
    }
  };

  // prologue: LDS0=B(0); bQ=B(1); afA=A(0); afB=A(1)
  loadB(0, bP);
  loadA(0, afA);
  loadB(1, bQ);
  writeB(0, bP);
  __syncthreads();
  loadA(1, afB);

  for (int kb=0; kb<16; kb+=2){
    // even step: compute LDS0/afA; stage B(kb+1)=bQ into LDS1; prefetch bP=B(kb+2), afA=A(kb+2)
    if (kb+2 < 16) loadB(kb+2, bP);
    compute(0, afA);
    if (kb+2 < 16) loadA(kb+2, afA);
    writeB(1, bQ);
    __syncthreads();
    // odd step kb+1: compute LDS1/afB; stage B(kb+2)=bP into LDS0; prefetch bQ=B(kb+3), afB=A(kb+3)
    if (kb+3 < 16) loadB(kb+3, bQ);
    compute(1, afB);
    if (kb+3 < 16) loadA(kb+3, afB);
    if (kb+2 < 16) writeB(0, bP);
    __syncthreads();
  }

  int nval = ne - m0; if (nval > 256) nval = 256;
  #pragma unroll
  for (int m=0;m<2;m++)
    #pragma unroll
    for (int n=0;n<2;n++)
      #pragma unroll
      for (int r=0;r<4;r++){
        int row = wid*32 + m*16 + (lane>>4)*4 + r;
        if (row < nval){
          float g = accg[m][n][r], u = accu[m][n][r];
          float sval = g / (1.f + __expf(-g)) * u;
          act[(size_t)(off0+m0+row)*IDIM + ibase + n*16 + (lane&15)] = f2bf(sval);
        }
      }
}

// ---------------- down GEMM ----------------
// tile M=256 x N=64, BK=64, 12 K-steps; 8 waves x 32 rows; same pipeline
__global__ __launch_bounds__(512,4) void k_down(const ushort* __restrict__ act,
    const float* __restrict__ w2, const int* __restrict__ offsets,
    const int* __restrict__ mtE, const int* __restrict__ mtM0, const int* __restrict__ nmt,
    float* __restrict__ pout){
  int bi  = blockIdx.x;
  int mti = bi >> 4;
  int ht  = bi & 15;
  if (mti >= nmt[0]) return;
  int e    = mtE[mti];
  int m0   = mtM0[mti];
  int off0 = offsets[e], ne = offsets[e+1]-off0;
  int hbase = ht*64;

  __shared__ ushort Bls[2][64][68];

  int tid = threadIdx.x, wid = tid>>6, lane = tid&63;
  int b_r = tid>>4, b_c4 = tid&15;
  const size_t wbase = (size_t)e * HDIM * IDIM;
  const float* bsrc0 = w2 + wbase + (size_t)(hbase+b_r   )*IDIM + b_c4*4;
  const float* bsrc1 = w2 + wbase + (size_t)(hbase+b_r+32)*IDIM + b_c4*4;

  int row0 = m0 + wid*32      + (lane&15); row0 = (row0 < ne) ? row0 : 0;
  int row1 = m0 + wid*32 + 16 + (lane&15); row1 = (row1 < ne) ? row1 : 0;
  const ushort* arow0 = act + (size_t)(off0+row0)*IDIM + (lane>>4)*8;
  const ushort* arow1 = act + (size_t)(off0+row1)*IDIM + (lane>>4)*8;

  f32x4 acc[2][4];
  #pragma unroll
  for (int a=0;a<2;a++)
    #pragma unroll
    for (int b=0;b<4;b++) acc[a][b]=(f32x4){0,0,0,0};

  float4 bP[2], bQ[2];
  bf16x8 afA[4], afB[4];

  auto loadB = [&](int kb, float4* d){
    d[0] = *(const float4*)(bsrc0 + kb*64);
    d[1] = *(const float4*)(bsrc1 + kb*64);
  };
  auto loadA = [&](int kb, bf16x8* d){
    #pragma unroll
    for (int kk=0;kk<2;kk++){
      d[kk*2+0] = *(const bf16x8*)(arow0 + kb*64 + kk*32);
      d[kk*2+1] = *(const bf16x8*)(arow1 + kb*64 + kk*32);
    }
  };
  auto writeB = [&](int buf, const float4* s){
    #pragma unroll
    for (int m=0;m<2;m++){
      ushort4 o; o.x=f2bf(s[m].x); o.y=f2bf(s[m].y); o.z=f2bf(s[m].z); o.w=f2bf(s[m].w);
      *(ushort4*)(&Bls[buf][b_r + m*32][b_c4*4]) = o;
    }
  };
  auto compute = [&](int buf, const bf16x8* af){
    #pragma unroll
    for (int kk=0;kk<2;kk++){
      #pragma unroll
      for (int n=0;n<4;n++){
        bf16x8 bw = *(const bf16x8*)(&Bls[buf][n*16 + (lane&15)][kk*32 + (lane>>4)*8]);
        #pragma unroll
        for (int m=0;m<2;m++)
          acc[m][n] = __builtin_amdgcn_mfma_f32_16x16x32_bf16(af[kk*2+m], bw, acc[m][n], 0,0,0);
      }
    }
  };

  loadB(0, bP);
  loadA(0, afA);
  loadB(1, bQ);
  writeB(0, bP);
  __syncthreads();
  loadA(1, afB);

  for (int kb=0; kb<12; kb+=2){
    if (kb+2 < 12) loadB(kb+2, bP);
    compute(0, afA);
    if (kb+2 < 12) loadA(kb+2, afA);
    writeB(1, bQ);
    __syncthreads();
    if (kb+3 < 12) loadB(kb+3, bQ);
    compute(1, afB);
    if (kb+3 < 12) loadA(kb+3, afB);
    if (kb+2 < 12) writeB(0, bP);
    __syncthreads();
  }

  int nval = ne - m0; if (nval > 256) nval = 256;
  #pragma unroll
  for (int m=0;m<2;m++)
    #pragma unroll
    for (int n=0;n<4;n++)
      #pragma unroll
      for (int r=0;r<4;r++){
        int row = wid*32 + m*16 + (lane>>4)*4 + r;
        if (row < nval)
          pout[(size_t)(off0+m0+row)*HDIM + hbase + n*16 + (lane&15)] = acc[m][n][r];
      }
}

// ---------------- combine ----------------
__global__ __launch_bounds__(256) void k_combine(const float* __restrict__ pout,
    const int* __restrict__ tk_slot, const float* __restrict__ wv,
    float* __restrict__ out){
  int t = blockIdx.x;
  int c = threadIdx.x;
  float a0=0,a1=0,a2=0,a3=0;
  #pragma unroll
  for (int k=0;k<TOPK;k++){
    int slot = tk_slot[t*TOPK+k];
    float w  = wv[t*TOPK+k];
    float4 v = *(const float4*)(pout + (size_t)slot*HDIM + c*4);
    a0 = fmaf(w, v.x, a0); a1 = fmaf(w, v.y, a1);
    a2 = fmaf(w, v.z, a2); a3 = fmaf(w, v.w, a3);
  }
  float4 o; o.x=a0; o.y=a1; o.z=a2; o.w=a3;
  *(float4*)(out + (size_t)t*HDIM + c*4) = o;
}

extern "C" void kernel_launch(void* const* d_in, const int* in_sizes, int n_in,
                              void* d_out, int out_size, void* d_ws, size_t ws_size,
                              hipStream_t stream){
  const float* x  = (const float*)d_in[0];
  const float* gw = (const float*)d_in[1];
  const float* w1 = (const float*)d_in[2];
  const float* w3 = (const float*)d_in[3];
  const float* w2 = (const float*)d_in[4];
  float* out = (float*)d_out;

  char* ws = (char*)d_ws;
  size_t off = 0;
  ushort* xb   = (ushort*)(ws + off); off += (size_t)T_TOK*HDIM*2;
  ushort* act  = (ushort*)(ws + off); off += (size_t)NPAIR*IDIM*2;
  float*  pout = (float*) (ws + off); off += (size_t)NPAIR*HDIM*4;
  int* counts  = (int*)(ws + off); off += NEXP*4;
  int* cursor  = (int*)(ws + off); off += NEXP*4;
  int* offsets = (int*)(ws + off); off += (NEXP+1)*4;
  int* mtE     = (int*)(ws + off); off += MAXMT*4;
  int* mtM0    = (int*)(ws + off); off += MAXMT*4;
  int* nmt     = (int*)(ws + off); off += 4;
  off = (off + 255) & ~(size_t)255;
  int*   ei      = (int*)  (ws + off); off += (size_t)NPAIR*4;
  float* wvp     = (float*)(ws + off); off += (size_t)NPAIR*4;
  int*   slot_tk = (int*)  (ws + off); off += (size_t)NPAIR*4;
  int*   tk_slot = (int*)  (ws + off); off += (size_t)NPAIR*4;

  hipMemsetAsync(counts, 0, 2*NEXP*4, stream);

  k_convert_x<<<T_TOK*HDIM/1024, 256, 0, stream>>>(x, xb);
  k_router<<<T_TOK/4, 256, 0, stream>>>(x, gw, ei, wvp, counts);
  k_offsets<<<1, 64, 0, stream>>>(counts, offsets, mtE, mtM0, nmt);
  k_scatter<<<NPAIR/256, 256, 0, stream>>>(ei, offsets, cursor, slot_tk, tk_slot);
  k_gateup<<<MAXMT*24, 512, 0, stream>>>(xb, w1, w3, offsets, slot_tk, mtE, mtM0, nmt, act);
  k_down<<<MAXMT*16, 512, 0, stream>>>(act, w2, offsets, mtE, mtM0, nmt, pout);
  k_combine<<<T_TOK, 256, 0, stream>>>(pout, tk_slot, wvp, out);
}